// Round 20
// baseline (94.171 us; speedup 1.0000x reference)
//
#include <hip/hip_runtime.h>
#include <math.h>

#define HH 512
#define WW 512
#define HB 64        // band height (8 bands per plane -> grid 992)
#define KR 4         // output rows per group
#define SUB 132      // uint2 slots per sub-array: 2+128+2 (halo+cols);
                     // 2*132 mod 32 == 8 -> write banks s*8+{0..14}: every
                     // bank exactly 2-way per 32-lane phase = FREE (m136).
#define ROWU2 (4 * SUB)     // 528 uint2 per row-tile
#define TILEU2 (4 * ROWU2)  // 2112 uint2 = 16896 B total (single buffer)

// R20 = R17 (92.5us best: f16 tile, SUB=132 conflict-free, imm-offset b64
// taps, light lgkm barriers, 17KB LDS, VGPR 56) + PACKED SSIM epilogue.
// R19 falsified the dispatch-tail theory (grid 2x -> neutral); cross-round
// evidence says runtime ~= sum of pipe times with VALU largest (58% busy),
// and the only VGPR-safe compressible instruction block left is the SSIM
// epilogue (~19 inst/pt scalar). Pack point-pairs into v2f (v_pk_*_f32):
// ~12.5 inst/pt. All other structure frozen. VGPR must stay <=64 (R15/R18:
// crossing the 64-cliff costs 20%+).

typedef float v2f __attribute__((ext_vector_type(2)));
typedef _Float16 h2 __attribute__((ext_vector_type(2)));

__device__ __forceinline__ void bar_lgkm() {
  asm volatile("s_waitcnt lgkmcnt(0)" ::: "memory");
  __builtin_amdgcn_s_barrier();
  __builtin_amdgcn_sched_barrier(0);
}

__device__ __forceinline__ unsigned pk16(float a, float b) {
  return __builtin_bit_cast(unsigned, __builtin_amdgcn_cvt_pkrtz(a, b));
}

__global__ __launch_bounds__(512, 1)
void ssim_main(const float* __restrict__ Pg, const float* __restrict__ Tg,
               float* __restrict__ partial) {
  __shared__ __align__(16) uint2 S2[TILEU2];   // 16896 B
  __shared__ float wsum[8];

  const int tid = threadIdx.x;            // vertical pass: column 0..511
  const int blk = blockIdx.x;
  const int plane = blk >> 3;
  const int band  = blk & 7;
  const int o0 = band * HB;               // first output row of band
  const float* __restrict__ P = Pg + (size_t)plane * (HH * WW);
  const float* __restrict__ T = Tg + (size_t)plane * (HH * WW);

  // zero tile once: halo slots (0,1,130,131 per sub-array) must stay 0
  // forever; interior slots 2..129 are fully overwritten every group.
  {
    const uint2 z = make_uint2(0u, 0u);
    for (int idx = tid; idx < TILEU2; idx += 512) S2[idx] = z;
  }

  // Gaussian weights, computed in double then rounded to f32 (matches jnp f32)
  float w[11];
  {
    double g[11], s = 0.0;
#pragma unroll
    for (int k = 0; k < 11; ++k) {
      double c = (double)(k - 5);
      g[k] = exp(-c * c / 4.5);
      s += g[k];
    }
#pragma unroll
    for (int k = 0; k < 11; ++k)
      w[k] = __uint_as_float(__builtin_amdgcn_readfirstlane(
                 __float_as_uint((float)(g[k] / s))));
  }
  // f16 weight pairs for the packed H-pass
  h2 wh[11];
#pragma unroll
  for (int k = 0; k < 11; ++k) {
    const _Float16 hw = (_Float16)w[k];
    wh[k][0] = hw; wh[k][1] = hw;
  }

  float sum = 0.f;
  const int jr = tid >> 7;                // H-pass: row within group (0..3)
  const int q  = tid & 127;               // H-pass: cols 4q..4q+3
  uint2* const rdbase = &S2[jr * ROWU2 + q + 2];
  uint2* const wrbase = &S2[(tid & 3) * SUB + (tid >> 2) + 2];

  // ---- rotating register ring (R12-proven): pr/tr[i] = input row rbase+i
  // (i=0..9); pn/tn = rows rbase+10..13 in flight. rbase = o0 + g - 5.
  float pr[10], tr[10], pn[4], tn[4];
#pragma unroll
  for (int i = 0; i < 10; ++i) {
    const int r = o0 - 5 + i;
    const bool v = (r >= 0);              // r <= o0+4 <= 452 < HH always
    pr[i] = v ? P[(size_t)r * WW + tid] : 0.f;
    tr[i] = v ? T[(size_t)r * WW + tid] : 0.f;
  }
#pragma unroll
  for (int i = 0; i < 4; ++i) {
    const int r = o0 + 5 + i;             // always in [5, 461]
    pn[i] = P[(size_t)r * WW + tid];
    tn[i] = T[(size_t)r * WW + tid];
  }

#define VACC(RI, PV, TV) {                                                 \
      const float p_ = (PV), t_ = (TV);                                   \
      const v2f pt  = {p_, t_};                                           \
      const v2f q23 = {fmaf(t_, t_, p_ * p_), p_ * t_};                   \
      _Pragma("unroll")                                                   \
      for (int j = 0; j < KR; ++j) {                                      \
        if ((RI) - j >= 0 && (RI) - j <= 10) {                            \
          const float wk = w[(RI) - j];                                   \
          const v2f wv = {wk, wk};                                        \
          apt[j] = __builtin_elementwise_fma(wv, pt,  apt[j]);            \
          asq[j] = __builtin_elementwise_fma(wv, q23, asq[j]);            \
        }                                                                 \
      }                                                                   \
    }

// VBLOCK(G): vertical sums for output rows G..G+3 into apt/asq (from ring),
// then rotate ring by 4 and issue the prefetch for rows o0+G+9..+12.
#define VBLOCK(G) {                                                        \
    { const v2f z = {0.f, 0.f};                                            \
      _Pragma("unroll")                                                    \
      for (int j = 0; j < KR; ++j) { apt[j] = z; asq[j] = z; } }           \
    _Pragma("unroll")                                                      \
    for (int ri = 0; ri < 10; ++ri) VACC(ri, pr[ri], tr[ri]);              \
    _Pragma("unroll")                                                      \
    for (int i = 0; i < 4; ++i) VACC(10 + i, pn[i], tn[i]);                \
    _Pragma("unroll")                                                      \
    for (int i = 0; i < 6; ++i) { pr[i] = pr[i + 4]; tr[i] = tr[i + 4]; }  \
    _Pragma("unroll")                                                      \
    for (int i = 0; i < 4; ++i) { pr[6 + i] = pn[i]; tr[6 + i] = tn[i]; }  \
    { const int prow = o0 + (G) + 9;                                       \
      if (prow + 3 < HH) {                                                 \
        _Pragma("unroll")                                                  \
        for (int i = 0; i < 4; ++i) {                                      \
          pn[i] = P[(size_t)(prow + i) * WW + tid];                        \
          tn[i] = T[(size_t)(prow + i) * WW + tid];                        \
        }                                                                  \
      } else {                                                             \
        _Pragma("unroll")                                                  \
        for (int i = 0; i < 4; ++i) {                                      \
          const int r = prow + i;                                          \
          const bool v = r < HH;                                           \
          pn[i] = v ? P[(size_t)r * WW + tid] : 0.f;                       \
          tn[i] = v ? T[(size_t)r * WW + tid] : 0.f;                       \
        }                                                                  \
      } }                                                                  \
  }

  v2f apt[KR], asq[KR];
  VBLOCK(0)                               // V for group 0; prefetch group 1

  for (int g = 0; g < HB; g += KR) {      // 16 groups of 4 output rows
    bar_lgkm();        // prior group's H reads done (g=0: zero-init visible)
#pragma unroll
    for (int j = 0; j < KR; ++j)
      wrbase[j * ROWU2] = make_uint2(pk16(apt[j][0], apt[j][1]),
                                     pk16(asq[j][0], asq[j][1]));
    bar_lgkm();        // stage visible to all waves
    // ---- big region: H(g) + SSIM + V(g+1) + prefetch (reg-only) ----
    h2 hpt[4], hsq[4];
    { const h2 z = {(_Float16)0.f, (_Float16)0.f};
#pragma unroll
      for (int m = 0; m < 4; ++m) { hpt[m] = z; hsq[m] = z; } }
#pragma unroll
    for (int k = 0; k < 14; ++k) {
      const int d = k - 5;
      const int s = d & 3;
      const int o = (d - s) >> 2;
      const uint2 vv = rdbase[s * SUB + o];
      const h2 va = __builtin_bit_cast(h2, vv.x);
      const h2 vb = __builtin_bit_cast(h2, vv.y);
#pragma unroll
      for (int m = 0; m < 4; ++m)
        if (k - m >= 0 && k - m <= 10) {
          hpt[m] = __builtin_elementwise_fma(wh[k - m], va, hpt[m]);
          hsq[m] = __builtin_elementwise_fma(wh[k - m], vb, hsq[m]);
        }
    }
    // ---- packed SSIM epilogue: 2 output points per v2f lane-pair ----
#pragma unroll
    for (int mp = 0; mp < 4; mp += 2) {
      const v2f mu_p = {(float)hpt[mp][0], (float)hpt[mp + 1][0]};
      const v2f mu_t = {(float)hpt[mp][1], (float)hpt[mp + 1][1]};
      const v2f s2v  = {(float)hsq[mp][0], (float)hsq[mp + 1][0]};
      const v2f scv  = {(float)hsq[mp][1], (float)hsq[mp + 1][1]};
      const v2f mp2 = mu_p * mu_p;
      const v2f mt2 = mu_t * mu_t;
      const v2f mct = mu_p * mu_t;
      const v2f msum = mp2 + mt2;
      const v2f zero = {0.f, 0.f};
      const v2f ssum = __builtin_elementwise_max(s2v - msum, zero);
      const v2f scd = scv - mct;
      const v2f two = {2.f, 2.f};
      const v2f c1v = {1.0e-4f, 1.0e-4f};
      const v2f c2v = {9.0e-4f, 9.0e-4f};
      const v2f num = __builtin_elementwise_fma(two, mct, c1v) *
                      __builtin_elementwise_fma(two, scd, c2v);
      const v2f den = (msum + c1v) * (ssum + c2v);
      sum += num[0] * __builtin_amdgcn_rcpf(den[0]);
      sum += num[1] * __builtin_amdgcn_rcpf(den[1]);
    }
    if (g + KR < HB) VBLOCK(g + KR)       // V for next group (reg-only)
  }
#undef VBLOCK
#undef VACC

  // block reduction of ssim partial sum
#pragma unroll
  for (int off = 32; off > 0; off >>= 1) sum += __shfl_down(sum, off, 64);
  if ((tid & 63) == 0) wsum[tid >> 6] = sum;
  __syncthreads();
  if (tid == 0) {
    float s = 0.f;
#pragma unroll
    for (int k2 = 0; k2 < 8; ++k2) s += wsum[k2];
    partial[blk] = s;
  }
}

__global__ void ssim_fin(const float* __restrict__ partial,
                         float* __restrict__ out, int n) {
  __shared__ double ws[4];
  double s = 0.0;
  for (int idx = threadIdx.x; idx < n; idx += 256) s += (double)partial[idx];
#pragma unroll
  for (int off = 32; off > 0; off >>= 1) s += __shfl_down(s, off, 64);
  if ((threadIdx.x & 63) == 0) ws[threadIdx.x >> 6] = s;
  __syncthreads();
  if (threadIdx.x == 0) {
    double tt = ws[0] + ws[1] + ws[2] + ws[3];
    out[0] = (float)(1.0 - tt / 32505856.0);
  }
}

extern "C" void kernel_launch(void* const* d_in, const int* in_sizes, int n_in,
                              void* d_out, int out_size, void* d_ws, size_t ws_size,
                              hipStream_t stream) {
  const float* pred = (const float*)d_in[0];
  const float* tgt  = (const float*)d_in[1];
  float* out        = (float*)d_out;
  float* partial    = (float*)d_ws;   // 992 floats of scratch

  ssim_main<<<dim3(992), dim3(512), 0, stream>>>(pred, tgt, partial);
  ssim_fin<<<dim3(1), dim3(256), 0, stream>>>(partial, out, 992);
}